// Round 7
// baseline (1185.592 us; speedup 1.0000x reference)
//
#include <hip/hip_runtime.h>
#include <stdint.h>

// NGCF forward. Node-factored:
//   s1[i] = sum_e norm_e * x[src_e],  c[i] = sum_e norm_e
//   aggr  = W1 s1 + W2 (x .* s1) + c*(b1+b2);  x' = leaky_relu(aggr)
// Gather: block = 16 nodes; CSR range of the block is contiguous, processed
// node-agnostically: 16 lanes/edge x 4 edges/instr, bf16 x rows (128 B),
// accumulate into LDS via ds_add_f32 (local node id packed in src's top byte,
// per-group feature rotation -> no same-address atomic serialization).
// Transform: MFMA 16x16x32 bf16 split hi/lo (~fp32). bf16 x shadow copy is
// ping-ponged across layers.

typedef __attribute__((ext_vector_type(8))) short short8v;
typedef __attribute__((ext_vector_type(4))) float f32x4;
typedef __attribute__((ext_vector_type(4))) unsigned short ushort4v;

struct EdgeIW { int src; float w; };  // src = node_src | (local<<24)

__device__ __forceinline__ unsigned short f2bf_rne(float f) {
  unsigned int u = __float_as_uint(f);
  unsigned int r = u + 0x7FFFu + ((u >> 16) & 1u);
  return (unsigned short)(r >> 16);
}
__device__ __forceinline__ float bf2f(unsigned short h) {
  return __uint_as_float(((unsigned int)h) << 16);
}

__global__ void k_count(const int* __restrict__ col, int E, unsigned int* __restrict__ deg) {
  int e = blockIdx.x * blockDim.x + threadIdx.x;
  if (e < E) atomicAdd(&deg[col[e]], 1u);
}

__global__ void k_scan1(const unsigned int* __restrict__ deg, unsigned int* __restrict__ incl,
                        unsigned int* __restrict__ bsum, int N) {
  __shared__ unsigned int sm[1024];
  int t = threadIdx.x;
  int i = blockIdx.x * 1024 + t;
  unsigned int v = (i < N) ? deg[i] : 0u;
  sm[t] = v;
  __syncthreads();
  for (int off = 1; off < 1024; off <<= 1) {
    unsigned int u = (t >= off) ? sm[t - off] : 0u;
    __syncthreads();
    sm[t] += u;
    __syncthreads();
  }
  if (i < N) incl[i] = sm[t];
  if (t == 1023) bsum[blockIdx.x] = sm[1023];
}

__global__ void k_scan2(const unsigned int* __restrict__ bsum, unsigned int* __restrict__ boff, int nblk) {
  if (blockIdx.x == 0 && threadIdx.x == 0) {
    unsigned int a = 0;
    for (int i = 0; i < nblk; ++i) { boff[i] = a; a += bsum[i]; }
  }
}

// rowptr/cursor + dis (fused)
__global__ void k_scan3(const unsigned int* __restrict__ deg, const unsigned int* __restrict__ incl,
                        const unsigned int* __restrict__ boff, unsigned int* __restrict__ rowptr,
                        unsigned int* __restrict__ cursor, float* __restrict__ dis, int N, int E) {
  int i = blockIdx.x * blockDim.x + threadIdx.x;
  if (i < N) {
    unsigned int ex = incl[i] - deg[i] + boff[i >> 10];
    rowptr[i] = ex;
    cursor[i] = ex;
    unsigned int d = deg[i];
    dis[i] = d ? rsqrtf((float)d) : 0.0f;
  }
  if (i == 0) rowptr[N] = (unsigned int)E;
}

__global__ void k_fill(const int* __restrict__ row, const int* __restrict__ col, int E,
                       const float* __restrict__ dis, unsigned int* __restrict__ cursor,
                       EdgeIW* __restrict__ iw) {
  int e = blockIdx.x * blockDim.x + threadIdx.x;
  if (e < E) {
    int r = row[e];
    int c = col[e];
    unsigned int pos = atomicAdd(&cursor[c], 1u);
    EdgeIW p;
    p.src = r | ((c & 15) << 24);   // pack local node id (block = 16 aligned)
    p.w = dis[r] * dis[c];
    iw[pos] = p;
  }
}

// x0 = concat(user_emb, item_emb) -> out cols [0,64) fp32 + bf16 shadow
__global__ void k_init(const float* __restrict__ ue, const float* __restrict__ ie,
                       float* __restrict__ out, unsigned short* __restrict__ xb0,
                       int Nu, int Ntot) {
  int idx = blockIdx.x * blockDim.x + threadIdx.x;
  if (idx >= Ntot * 16) return;
  int n = idx >> 4;
  int q = idx & 15;
  f32x4 v = (n < Nu) ? *(const f32x4*)(ue + (size_t)n * 64 + q * 4)
                     : *(const f32x4*)(ie + (size_t)(n - Nu) * 64 + q * 4);
  *(f32x4*)(out + (size_t)n * 256 + q * 4) = v;
  ushort4v h;
#pragma unroll
  for (int k = 0; k < 4; ++k) h[k] = f2bf_rne(v[k]);
  *(ushort4v*)(xb0 + (size_t)n * 64 + q * 4) = h;
}

// Pack W1/W2 (3 layers) into MFMA B-fragment order, split hi/lo bf16.
// Flat dst index = ((((((l*2+mat)*2+hl)*4+ob)*2+ks)*64+lane)*8+j)
// B[k][n] = W[out=n][k]; lane: n = 16*ob + (lane&15), k = 32*ks + 8*(lane>>4) + j.
__global__ void k_prepw(const float* __restrict__ W1, const float* __restrict__ b1,
                        const float* __restrict__ W2, const float* __restrict__ b2,
                        unsigned short* __restrict__ Wf, float* __restrict__ bbsum) {
  int idx = blockIdx.x * blockDim.x + threadIdx.x;
  const int total = 3 * 2 * 2 * 4 * 2 * 64 * 8;  // 49152
  if (idx < total) {
    int j    = idx & 7;
    int lane = (idx >> 3) & 63;
    int ks   = (idx >> 9) & 1;
    int ob   = (idx >> 10) & 3;
    int hl   = (idx >> 12) & 1;
    int mat  = (idx >> 13) & 1;
    int l    = idx >> 14;
    int out_f = ob * 16 + (lane & 15);
    int k = ks * 32 + (lane >> 4) * 8 + j;
    const float* W = (mat ? W2 : W1) + (size_t)l * 64 * 64;
    float w = W[out_f * 64 + k];
    unsigned short hi = f2bf_rne(w);
    unsigned short val = hi;
    if (hl == 1) val = f2bf_rne(w - bf2f(hi));
    Wf[idx] = val;
  }
  if (idx < 3 * 64) {
    bbsum[idx] = b1[idx] + b2[idx];
  }
}

// One block = 16 nodes, 128 threads (2 waves). Node-agnostic contiguous
// edge-range gather into LDS atomics, then MFMA transform.
__global__ __launch_bounds__(128, 7) void k_layer(
    const unsigned int* __restrict__ rowptr, const EdgeIW* __restrict__ iw,
    const unsigned short* __restrict__ xbr,  // x bf16 (read) [N][64]
    unsigned short* __restrict__ xbw,        // next x bf16 (write), if wr_next
    float* __restrict__ out,
    const unsigned short* __restrict__ Wf,   // per-layer base, 16384 ushorts
    const float* __restrict__ bb,            // per-layer base, 64
    int N, int pcol, int lcol, int wr_next)
{
  __shared__ float tS[16][66];
  __shared__ float cLs[16];

  const int tid = (int)threadIdx.x;
  const int w = tid >> 6;
  const int lane = tid & 63;
  const int base = (int)blockIdx.x * 16;

  // zero accumulators
  for (int i = tid; i < 16 * 66; i += 128) ((float*)tS)[i] = 0.f;
  if (tid < 16) cLs[tid] = 0.f;
  __syncthreads();

  // contiguous edge range of this block's 16 nodes, split across 2 waves
  int top = base + 16; if (top > N) top = N;
  unsigned int s = rowptr[base];
  unsigned int t = rowptr[top];
  unsigned int half = (t - s) >> 1;
  unsigned int e = s + (w ? half : 0);
  unsigned int e1 = w ? t : s + half;

  const int g = lane >> 4;        // edge slot in 4-edge group
  const int j = lane & 15;        // feature-quad index
  const int jr = (j + g) & 15;    // rotated quad -> disjoint atomic addresses

  auto ldx = [&](EdgeIW p) -> ushort4v {
    return *(const ushort4v*)(xbr + (((size_t)((unsigned)p.src & 0xFFFFFFu)) << 6) + 4 * jr);
  };
  auto proc = [&](EdgeIW p, ushort4v xv) {
    int local = ((unsigned)p.src) >> 24;
    float wv = p.w;
    float* rowp = &tS[local][4 * jr];
    atomicAdd(&rowp[0], wv * bf2f(xv[0]));
    atomicAdd(&rowp[1], wv * bf2f(xv[1]));
    atomicAdd(&rowp[2], wv * bf2f(xv[2]));
    atomicAdd(&rowp[3], wv * bf2f(xv[3]));
    if (j == 0) atomicAdd(&cLs[local], wv);
  };

  for (; e + 16 <= e1; e += 16) {
    EdgeIW p0 = iw[e + g];
    EdgeIW p1 = iw[e + 4 + g];
    EdgeIW p2 = iw[e + 8 + g];
    EdgeIW p3 = iw[e + 12 + g];
    ushort4v x0 = ldx(p0);
    ushort4v x1 = ldx(p1);
    ushort4v x2 = ldx(p2);
    ushort4v x3 = ldx(p3);
    proc(p0, x0);
    proc(p1, x1);
    proc(p2, x2);
    proc(p3, x3);
  }
  for (; e < e1; e += 4) {
    unsigned int ee = e + (unsigned int)g;
    if (ee < e1) {
      EdgeIW p = iw[ee];
      proc(p, ldx(p));
    }
  }
  __syncthreads();

  // ---- MFMA transform: wave w handles output blocks ob = 2w, 2w+1 ----
  const int m = lane & 15;
  const int gg = lane >> 4;
  const int rn = (base + m < N) ? (base + m) : (N - 1);

  float bb0 = bb[(2 * w + 0) * 16 + m];
  float bb1 = bb[(2 * w + 1) * 16 + m];
  float cn[4];
#pragma unroll
  for (int r = 0; r < 4; ++r) cn[r] = cLs[gg * 4 + r];

  f32x4 accP, accQ;
#pragma unroll
  for (int r = 0; r < 4; ++r) { accP[r] = cn[r] * bb0; accQ[r] = cn[r] * bb1; }

  auto ldW = [&](int mat, int hl, int ob, int ks) -> short8v {
    return *(const short8v*)(Wf + (size_t)((((((mat * 2 + hl) * 4 + ob) * 2 + ks) << 6) + lane) << 3));
  };

#pragma unroll
  for (int ks = 0; ks < 2; ++ks) {
    const float* xrow = out + (size_t)rn * 256 + pcol + ks * 32 + gg * 8;
    f32x4 x0 = *(const f32x4*)xrow;
    f32x4 x1 = *(const f32x4*)(xrow + 4);
    short8v ASh, ASl, AHh, AHl;
#pragma unroll
    for (int jj = 0; jj < 8; ++jj) {
      float vs = tS[m][ks * 32 + gg * 8 + jj];
      float vx = (jj < 4) ? x0[jj & 3] : x1[jj & 3];
      float vh = vx * vs;
      unsigned short h1 = f2bf_rne(vs);
      ASh[jj] = (short)h1;
      ASl[jj] = (short)f2bf_rne(vs - bf2f(h1));
      unsigned short h2 = f2bf_rne(vh);
      AHh[jj] = (short)h2;
      AHl[jj] = (short)f2bf_rne(vh - bf2f(h2));
    }
    {
      const int ob = 2 * w;
      short8v B1h = ldW(0, 0, ob, ks), B1l = ldW(0, 1, ob, ks);
      short8v B2h = ldW(1, 0, ob, ks), B2l = ldW(1, 1, ob, ks);
      accP = __builtin_amdgcn_mfma_f32_16x16x32_bf16(ASh, B1h, accP, 0, 0, 0);
      accP = __builtin_amdgcn_mfma_f32_16x16x32_bf16(ASl, B1h, accP, 0, 0, 0);
      accP = __builtin_amdgcn_mfma_f32_16x16x32_bf16(ASh, B1l, accP, 0, 0, 0);
      accP = __builtin_amdgcn_mfma_f32_16x16x32_bf16(AHh, B2h, accP, 0, 0, 0);
      accP = __builtin_amdgcn_mfma_f32_16x16x32_bf16(AHl, B2h, accP, 0, 0, 0);
      accP = __builtin_amdgcn_mfma_f32_16x16x32_bf16(AHh, B2l, accP, 0, 0, 0);
    }
    {
      const int ob = 2 * w + 1;
      short8v B1h = ldW(0, 0, ob, ks), B1l = ldW(0, 1, ob, ks);
      short8v B2h = ldW(1, 0, ob, ks), B2l = ldW(1, 1, ob, ks);
      accQ = __builtin_amdgcn_mfma_f32_16x16x32_bf16(ASh, B1h, accQ, 0, 0, 0);
      accQ = __builtin_amdgcn_mfma_f32_16x16x32_bf16(ASl, B1h, accQ, 0, 0, 0);
      accQ = __builtin_amdgcn_mfma_f32_16x16x32_bf16(ASh, B1l, accQ, 0, 0, 0);
      accQ = __builtin_amdgcn_mfma_f32_16x16x32_bf16(AHh, B2h, accQ, 0, 0, 0);
      accQ = __builtin_amdgcn_mfma_f32_16x16x32_bf16(AHl, B2h, accQ, 0, 0, 0);
      accQ = __builtin_amdgcn_mfma_f32_16x16x32_bf16(AHh, B2l, accQ, 0, 0, 0);
    }
  }
  // C/D: col = lane&15 (out feature), row = gg*4 + r (node within 16)
#pragma unroll
  for (int r = 0; r < 4; ++r) {
    int n = base + gg * 4 + r;
    if (n < N) {
      float v = accP[r];
      v = (v > 0.0f) ? v : 0.01f * v;
      out[(size_t)n * 256 + lcol + (2 * w) * 16 + m] = v;
      float q = accQ[r];
      q = (q > 0.0f) ? q : 0.01f * q;
      out[(size_t)n * 256 + lcol + (2 * w + 1) * 16 + m] = q;
      if (wr_next) {
        xbw[(size_t)n * 64 + (2 * w) * 16 + m] = f2bf_rne(v);
        xbw[(size_t)n * 64 + (2 * w + 1) * 16 + m] = f2bf_rne(q);
      }
    }
  }
}

extern "C" void kernel_launch(void* const* d_in, const int* in_sizes, int n_in,
                              void* d_out, int out_size, void* d_ws, size_t ws_size,
                              hipStream_t stream) {
  const int* eidx = (const int*)d_in[0];
  const float* ue = (const float*)d_in[1];
  const float* ie = (const float*)d_in[2];
  const float* W1 = (const float*)d_in[3];
  const float* b1 = (const float*)d_in[4];
  const float* W2 = (const float*)d_in[5];
  const float* b2 = (const float*)d_in[6];

  const int E = in_sizes[0] / 2;
  const int Nu = in_sizes[1] / 64;
  const int Ni = in_sizes[2] / 64;
  const int N = Nu + Ni;
  const int* row = eidx;
  const int* colp = eidx + E;
  float* out = (float*)d_out;

  char* ws = (char*)d_ws;
  size_t off = 0;
  auto alloc = [&](size_t bytes) -> void* {
    void* p = ws + off;
    off += (bytes + 255) & ~(size_t)255;
    return p;
  };
  unsigned int* deg    = (unsigned int*)alloc((size_t)N * 4);
  unsigned int* cursor = (unsigned int*)alloc((size_t)N * 4);
  unsigned int* rowptr = (unsigned int*)alloc((size_t)(N + 1) * 4);
  float*        dis    = (float*)alloc((size_t)N * 4);
  unsigned int* incl   = (unsigned int*)alloc((size_t)N * 4);
  unsigned int* bsum   = (unsigned int*)alloc(1024 * 4);
  unsigned int* boff   = (unsigned int*)alloc(1024 * 4);
  EdgeIW*       iw     = (EdgeIW*)alloc((size_t)E * 8);
  unsigned short* Wf   = (unsigned short*)alloc((size_t)3 * 16384 * 2);
  float*        bbsum  = (float*)alloc((size_t)3 * 64 * 4);
  unsigned short* xbf0 = (unsigned short*)alloc((size_t)N * 64 * 2);
  unsigned short* xbf1 = (unsigned short*)alloc((size_t)N * 64 * 2);
  (void)ws_size;

  hipMemsetAsync(deg, 0, (size_t)N * 4, stream);

  const int blkE = (E + 255) / 256;
  const int blkN = (N + 255) / 256;
  const int nblk = (N + 1023) / 1024;

  k_count<<<blkE, 256, 0, stream>>>(colp, E, deg);
  k_scan1<<<nblk, 1024, 0, stream>>>(deg, incl, bsum, N);
  k_scan2<<<1, 64, 0, stream>>>(bsum, boff, nblk);
  k_scan3<<<blkN, 256, 0, stream>>>(deg, incl, boff, rowptr, cursor, dis, N, E);
  k_fill<<<blkE, 256, 0, stream>>>(row, colp, E, dis, cursor, iw);
  k_init<<<(N * 16 + 255) / 256, 256, 0, stream>>>(ue, ie, out, xbf0, Nu, N);
  k_prepw<<<192, 256, 0, stream>>>(W1, b1, W2, b2, Wf, bbsum);

  unsigned short* xb[2] = { xbf0, xbf1 };
  const int nt = (N + 15) / 16;
  for (int l = 0; l < 3; ++l) {
    int pcol = l * 64;
    int lcol = (l + 1) * 64;
    k_layer<<<nt, 128, 0, stream>>>(rowptr, iw, xb[l & 1], xb[(l + 1) & 1], out,
                                    Wf + (size_t)l * 16384, bbsum + (size_t)l * 64,
                                    N, pcol, lcol, (l < 2) ? 1 : 0);
  }
}

// Round 8
// 272.333 us; speedup vs baseline: 4.3535x; 4.3535x over previous
//
#include <hip/hip_runtime.h>
#include <stdint.h>

// NGCF forward. Node-factored:
//   s1[i] = sum_e norm_e * x[src_e],  c[i] = sum_e norm_e
//   aggr  = W1 s1 + W2 (x .* s1) + c*(b1+b2);  x' = leaky_relu(aggr)
// Gather: 16-node blocks (128 thr / 2 waves), node PAIRS, half-wave per edge,
// lane j covers features 2j,2j+1 read as 2xbf16 (uint) from a bf16 shadow of
// x (128 B rows, 12.8 MB working set), fp32 register accumulation.
// Transform: MFMA 16x16x32 bf16 split hi/lo (~fp32). bf16 shadow ping-pongs
// across layers (epilogue writes next layer's copy).
// [R7 lesson: LDS-atomic accumulation = 6x regression; register accum only.]

typedef __attribute__((ext_vector_type(8))) short short8v;
typedef __attribute__((ext_vector_type(4))) float f32x4;
typedef __attribute__((ext_vector_type(2))) float f32x2;
typedef __attribute__((ext_vector_type(4))) unsigned short ushort4v;

struct EdgeIW { int src; float w; };  // interleaved CSR payload, 8B

__device__ __forceinline__ unsigned short f2bf_rne(float f) {
  unsigned int u = __float_as_uint(f);
  unsigned int r = u + 0x7FFFu + ((u >> 16) & 1u);
  return (unsigned short)(r >> 16);
}
__device__ __forceinline__ float bf2f(unsigned short h) {
  return __uint_as_float(((unsigned int)h) << 16);
}

__global__ void k_count(const int* __restrict__ col, int E, unsigned int* __restrict__ deg) {
  int e = blockIdx.x * blockDim.x + threadIdx.x;
  if (e < E) atomicAdd(&deg[col[e]], 1u);
}

__global__ void k_scan1(const unsigned int* __restrict__ deg, unsigned int* __restrict__ incl,
                        unsigned int* __restrict__ bsum, int N) {
  __shared__ unsigned int sm[1024];
  int t = threadIdx.x;
  int i = blockIdx.x * 1024 + t;
  unsigned int v = (i < N) ? deg[i] : 0u;
  sm[t] = v;
  __syncthreads();
  for (int off = 1; off < 1024; off <<= 1) {
    unsigned int u = (t >= off) ? sm[t - off] : 0u;
    __syncthreads();
    sm[t] += u;
    __syncthreads();
  }
  if (i < N) incl[i] = sm[t];
  if (t == 1023) bsum[blockIdx.x] = sm[1023];
}

__global__ void k_scan2(const unsigned int* __restrict__ bsum, unsigned int* __restrict__ boff, int nblk) {
  if (blockIdx.x == 0 && threadIdx.x == 0) {
    unsigned int a = 0;
    for (int i = 0; i < nblk; ++i) { boff[i] = a; a += bsum[i]; }
  }
}

// rowptr/cursor + dis (fused)
__global__ void k_scan3(const unsigned int* __restrict__ deg, const unsigned int* __restrict__ incl,
                        const unsigned int* __restrict__ boff, unsigned int* __restrict__ rowptr,
                        unsigned int* __restrict__ cursor, float* __restrict__ dis, int N, int E) {
  int i = blockIdx.x * blockDim.x + threadIdx.x;
  if (i < N) {
    unsigned int ex = incl[i] - deg[i] + boff[i >> 10];
    rowptr[i] = ex;
    cursor[i] = ex;
    unsigned int d = deg[i];
    dis[i] = d ? rsqrtf((float)d) : 0.0f;
  }
  if (i == 0) rowptr[N] = (unsigned int)E;
}

__global__ void k_fill(const int* __restrict__ row, const int* __restrict__ col, int E,
                       const float* __restrict__ dis, unsigned int* __restrict__ cursor,
                       EdgeIW* __restrict__ iw) {
  int e = blockIdx.x * blockDim.x + threadIdx.x;
  if (e < E) {
    int r = row[e];
    int c = col[e];
    unsigned int pos = atomicAdd(&cursor[c], 1u);
    EdgeIW p;
    p.src = r;
    p.w = dis[r] * dis[c];
    iw[pos] = p;
  }
}

// x0 = concat(user_emb, item_emb) -> out cols [0,64) fp32 + bf16 shadow
__global__ void k_init(const float* __restrict__ ue, const float* __restrict__ ie,
                       float* __restrict__ out, unsigned short* __restrict__ xb0,
                       int Nu, int Ntot) {
  int idx = blockIdx.x * blockDim.x + threadIdx.x;
  if (idx >= Ntot * 16) return;
  int n = idx >> 4;
  int q = idx & 15;
  f32x4 v = (n < Nu) ? *(const f32x4*)(ue + (size_t)n * 64 + q * 4)
                     : *(const f32x4*)(ie + (size_t)(n - Nu) * 64 + q * 4);
  *(f32x4*)(out + (size_t)n * 256 + q * 4) = v;
  ushort4v h;
#pragma unroll
  for (int k = 0; k < 4; ++k) h[k] = f2bf_rne(v[k]);
  *(ushort4v*)(xb0 + (size_t)n * 64 + q * 4) = h;
}

// Pack W1/W2 (3 layers) into MFMA B-fragment order, split hi/lo bf16.
// Flat dst index = ((((((l*2+mat)*2+hl)*4+ob)*2+ks)*64+lane)*8+j)
// B[k][n] = W[out=n][k]; lane: n = 16*ob + (lane&15), k = 32*ks + 8*(lane>>4) + j.
__global__ void k_prepw(const float* __restrict__ W1, const float* __restrict__ b1,
                        const float* __restrict__ W2, const float* __restrict__ b2,
                        unsigned short* __restrict__ Wf, float* __restrict__ bbsum) {
  int idx = blockIdx.x * blockDim.x + threadIdx.x;
  const int total = 3 * 2 * 2 * 4 * 2 * 64 * 8;  // 49152
  if (idx < total) {
    int j    = idx & 7;
    int lane = (idx >> 3) & 63;
    int ks   = (idx >> 9) & 1;
    int ob   = (idx >> 10) & 3;
    int hl   = (idx >> 12) & 1;
    int mat  = (idx >> 13) & 1;
    int l    = idx >> 14;
    int out_f = ob * 16 + (lane & 15);
    int k = ks * 32 + (lane >> 4) * 8 + j;
    const float* W = (mat ? W2 : W1) + (size_t)l * 64 * 64;
    float w = W[out_f * 64 + k];
    unsigned short hi = f2bf_rne(w);
    unsigned short val = hi;
    if (hl == 1) val = f2bf_rne(w - bf2f(hi));
    Wf[idx] = val;
  }
  if (idx < 3 * 64) {
    bbsum[idx] = b1[idx] + b2[idx];
  }
}

// One block = 16 nodes = 2 waves x 8 nodes. bf16 two-feature gather.
__global__ __launch_bounds__(128, 7) void k_layer(
    const unsigned int* __restrict__ rowptr, const EdgeIW* __restrict__ iw,
    const unsigned short* __restrict__ xbr,  // x bf16 (read) [N][64]
    unsigned short* __restrict__ xbw,        // next x bf16 (write), if wr_next
    float* __restrict__ out,
    const unsigned short* __restrict__ Wf,   // per-layer base, 16384 ushorts
    const float* __restrict__ bb,            // per-layer base, 64
    int N, int pcol, int lcol, int wr_next)
{
  __shared__ float tS[16][66];
  __shared__ float cL[16];

  const int w = (int)threadIdx.x >> 6;
  const int lane = (int)threadIdx.x & 63;
  const int h = lane >> 5;     // which edge of the 2-edge batch
  const int j = lane & 31;     // feature-pair index (features 2j, 2j+1)
  const int base = (int)blockIdx.x * 16;
  const unsigned short* xq = xbr + 2 * j;

#define FMA2(acc, p, v) { acc.x = fmaf(p.w, v.x, acc.x); acc.y = fmaf(p.w, v.y, acc.y); }
#define LD2(p) ({ unsigned int _u = *(const unsigned int*)(xq + (((size_t)(unsigned)(p).src) << 6)); \
                  f32x2 _v; _v.x = bf2f((unsigned short)_u); _v.y = bf2f((unsigned short)(_u >> 16)); _v; })

  // ---- gather phase: wave w owns rows [8w,8w+8), as 4 node-pairs ----
  for (int i0 = 0; i0 < 8; i0 += 2) {
    const int iA = w * 8 + i0, iB = iA + 1;
    int nA = base + iA, nB = base + iB;
    unsigned int eA = 0, endA = 0, eB = 0, endB = 0;
    if (nA < N) { eA = rowptr[nA]; endA = rowptr[nA + 1]; }
    if (nB < N) { eB = rowptr[nB]; endB = rowptr[nB + 1]; }
    f32x2 aA0 = {0.f, 0.f}, aA1 = {0.f, 0.f}, aB0 = {0.f, 0.f}, aB1 = {0.f, 0.f};
    float cA = 0.f, cB = 0.f;
    while (eA + 4 <= endA && eB + 4 <= endB) {
      EdgeIW pA0 = iw[eA + h];
      EdgeIW pA1 = iw[eA + 2 + h];
      EdgeIW pB0 = iw[eB + h];
      EdgeIW pB1 = iw[eB + 2 + h];
      f32x2 vA0 = LD2(pA0);
      f32x2 vA1 = LD2(pA1);
      f32x2 vB0 = LD2(pB0);
      f32x2 vB1 = LD2(pB1);
      FMA2(aA0, pA0, vA0); FMA2(aA1, pA1, vA1);
      FMA2(aB0, pB0, vB0); FMA2(aB1, pB1, vB1);
      cA += pA0.w + pA1.w;
      cB += pB0.w + pB1.w;
      eA += 4; eB += 4;
    }
    while (eA + 4 <= endA) {
      EdgeIW p0 = iw[eA + h];
      EdgeIW p1 = iw[eA + 2 + h];
      f32x2 v0 = LD2(p0);
      f32x2 v1 = LD2(p1);
      FMA2(aA0, p0, v0); FMA2(aA1, p1, v1);
      cA += p0.w + p1.w;
      eA += 4;
    }
    while (eB + 4 <= endB) {
      EdgeIW p0 = iw[eB + h];
      EdgeIW p1 = iw[eB + 2 + h];
      f32x2 v0 = LD2(p0);
      f32x2 v1 = LD2(p1);
      FMA2(aB0, p0, v0); FMA2(aB1, p1, v1);
      cB += p0.w + p1.w;
      eB += 4;
    }
    if (eA < endA) {
      int r = (int)(endA - eA);
      if (h < r) { EdgeIW p = iw[eA + h]; f32x2 v = LD2(p); FMA2(aA0, p, v); cA += p.w; }
      if (2 + h < r) { EdgeIW p = iw[eA + 2 + h]; f32x2 v = LD2(p); FMA2(aA1, p, v); cA += p.w; }
    }
    if (eB < endB) {
      int r = (int)(endB - eB);
      if (h < r) { EdgeIW p = iw[eB + h]; f32x2 v = LD2(p); FMA2(aB0, p, v); cB += p.w; }
      if (2 + h < r) { EdgeIW p = iw[eB + 2 + h]; f32x2 v = LD2(p); FMA2(aB1, p, v); cB += p.w; }
    }
    // combine 2 chains, then the two half-waves (edge slots)
    f32x2 sA, sB;
    sA.x = aA0.x + aA1.x; sA.y = aA0.y + aA1.y;
    sB.x = aB0.x + aB1.x; sB.y = aB0.y + aB1.y;
    sA.x += __shfl_xor(sA.x, 32); sA.y += __shfl_xor(sA.y, 32);
    sB.x += __shfl_xor(sB.x, 32); sB.y += __shfl_xor(sB.y, 32);
    cA += __shfl_xor(cA, 32);
    cB += __shfl_xor(cB, 32);
    if (h == 0) {
      *(f32x2*)&tS[iA][2 * j] = sA;
      *(f32x2*)&tS[iB][2 * j] = sB;
    }
    if (lane == 0) { cL[iA] = cA; cL[iB] = cB; }
  }
  __syncthreads();

  // ---- MFMA transform: wave w handles output blocks ob = 2w, 2w+1 ----
  const int m = lane & 15;
  const int g = lane >> 4;
  const int rn = (base + m < N) ? (base + m) : (N - 1);

  float bb0 = bb[(2 * w + 0) * 16 + m];
  float bb1 = bb[(2 * w + 1) * 16 + m];
  float cn[4];
#pragma unroll
  for (int r = 0; r < 4; ++r) cn[r] = cL[g * 4 + r];

  f32x4 accP, accQ;
#pragma unroll
  for (int r = 0; r < 4; ++r) { accP[r] = cn[r] * bb0; accQ[r] = cn[r] * bb1; }

  auto ldW = [&](int mat, int hl, int ob, int ks) -> short8v {
    return *(const short8v*)(Wf + (size_t)((((((mat * 2 + hl) * 4 + ob) * 2 + ks) << 6) + lane) << 3));
  };

#pragma unroll
  for (int ks = 0; ks < 2; ++ks) {
    const float* xrow = out + (size_t)rn * 256 + pcol + ks * 32 + g * 8;
    f32x4 x0 = *(const f32x4*)xrow;
    f32x4 x1 = *(const f32x4*)(xrow + 4);
    short8v ASh, ASl, AHh, AHl;
#pragma unroll
    for (int jj = 0; jj < 8; ++jj) {
      float vs = tS[m][ks * 32 + g * 8 + jj];
      float vx = (jj < 4) ? x0[jj & 3] : x1[jj & 3];
      float vh = vx * vs;
      unsigned short h1 = f2bf_rne(vs);
      ASh[jj] = (short)h1;
      ASl[jj] = (short)f2bf_rne(vs - bf2f(h1));
      unsigned short h2 = f2bf_rne(vh);
      AHh[jj] = (short)h2;
      AHl[jj] = (short)f2bf_rne(vh - bf2f(h2));
    }
    {
      const int ob = 2 * w;
      short8v B1h = ldW(0, 0, ob, ks), B1l = ldW(0, 1, ob, ks);
      short8v B2h = ldW(1, 0, ob, ks), B2l = ldW(1, 1, ob, ks);
      accP = __builtin_amdgcn_mfma_f32_16x16x32_bf16(ASh, B1h, accP, 0, 0, 0);
      accP = __builtin_amdgcn_mfma_f32_16x16x32_bf16(ASl, B1h, accP, 0, 0, 0);
      accP = __builtin_amdgcn_mfma_f32_16x16x32_bf16(ASh, B1l, accP, 0, 0, 0);
      accP = __builtin_amdgcn_mfma_f32_16x16x32_bf16(AHh, B2h, accP, 0, 0, 0);
      accP = __builtin_amdgcn_mfma_f32_16x16x32_bf16(AHl, B2h, accP, 0, 0, 0);
      accP = __builtin_amdgcn_mfma_f32_16x16x32_bf16(AHh, B2l, accP, 0, 0, 0);
    }
    {
      const int ob = 2 * w + 1;
      short8v B1h = ldW(0, 0, ob, ks), B1l = ldW(0, 1, ob, ks);
      short8v B2h = ldW(1, 0, ob, ks), B2l = ldW(1, 1, ob, ks);
      accQ = __builtin_amdgcn_mfma_f32_16x16x32_bf16(ASh, B1h, accQ, 0, 0, 0);
      accQ = __builtin_amdgcn_mfma_f32_16x16x32_bf16(ASl, B1h, accQ, 0, 0, 0);
      accQ = __builtin_amdgcn_mfma_f32_16x16x32_bf16(ASh, B1l, accQ, 0, 0, 0);
      accQ = __builtin_amdgcn_mfma_f32_16x16x32_bf16(AHh, B2h, accQ, 0, 0, 0);
      accQ = __builtin_amdgcn_mfma_f32_16x16x32_bf16(AHl, B2h, accQ, 0, 0, 0);
      accQ = __builtin_amdgcn_mfma_f32_16x16x32_bf16(AHh, B2l, accQ, 0, 0, 0);
    }
  }
  // C/D: col = lane&15 (out feature), row = g*4 + r (node within 16)
#pragma unroll
  for (int r = 0; r < 4; ++r) {
    int n = base + g * 4 + r;
    if (n < N) {
      float v = accP[r];
      v = (v > 0.0f) ? v : 0.01f * v;
      out[(size_t)n * 256 + lcol + (2 * w) * 16 + m] = v;
      float q = accQ[r];
      q = (q > 0.0f) ? q : 0.01f * q;
      out[(size_t)n * 256 + lcol + (2 * w + 1) * 16 + m] = q;
      if (wr_next) {
        xbw[(size_t)n * 64 + (2 * w) * 16 + m] = f2bf_rne(v);
        xbw[(size_t)n * 64 + (2 * w + 1) * 16 + m] = f2bf_rne(q);
      }
    }
  }
#undef FMA2
#undef LD2
}

extern "C" void kernel_launch(void* const* d_in, const int* in_sizes, int n_in,
                              void* d_out, int out_size, void* d_ws, size_t ws_size,
                              hipStream_t stream) {
  const int* eidx = (const int*)d_in[0];
  const float* ue = (const float*)d_in[1];
  const float* ie = (const float*)d_in[2];
  const float* W1 = (const float*)d_in[3];
  const float* b1 = (const float*)d_in[4];
  const float* W2 = (const float*)d_in[5];
  const float* b2 = (const float*)d_in[6];

  const int E = in_sizes[0] / 2;
  const int Nu = in_sizes[1] / 64;
  const int Ni = in_sizes[2] / 64;
  const int N = Nu + Ni;
  const int* row = eidx;
  const int* colp = eidx + E;
  float* out = (float*)d_out;

  char* ws = (char*)d_ws;
  size_t off = 0;
  auto alloc = [&](size_t bytes) -> void* {
    void* p = ws + off;
    off += (bytes + 255) & ~(size_t)255;
    return p;
  };
  unsigned int* deg    = (unsigned int*)alloc((size_t)N * 4);
  unsigned int* cursor = (unsigned int*)alloc((size_t)N * 4);
  unsigned int* rowptr = (unsigned int*)alloc((size_t)(N + 1) * 4);
  float*        dis    = (float*)alloc((size_t)N * 4);
  unsigned int* incl   = (unsigned int*)alloc((size_t)N * 4);
  unsigned int* bsum   = (unsigned int*)alloc(1024 * 4);
  unsigned int* boff   = (unsigned int*)alloc(1024 * 4);
  EdgeIW*       iw     = (EdgeIW*)alloc((size_t)E * 8);
  unsigned short* Wf   = (unsigned short*)alloc((size_t)3 * 16384 * 2);
  float*        bbsum  = (float*)alloc((size_t)3 * 64 * 4);
  unsigned short* xbf0 = (unsigned short*)alloc((size_t)N * 64 * 2);
  unsigned short* xbf1 = (unsigned short*)alloc((size_t)N * 64 * 2);
  (void)ws_size;

  hipMemsetAsync(deg, 0, (size_t)N * 4, stream);

  const int blkE = (E + 255) / 256;
  const int blkN = (N + 255) / 256;
  const int nblk = (N + 1023) / 1024;

  k_count<<<blkE, 256, 0, stream>>>(colp, E, deg);
  k_scan1<<<nblk, 1024, 0, stream>>>(deg, incl, bsum, N);
  k_scan2<<<1, 64, 0, stream>>>(bsum, boff, nblk);
  k_scan3<<<blkN, 256, 0, stream>>>(deg, incl, boff, rowptr, cursor, dis, N, E);
  k_fill<<<blkE, 256, 0, stream>>>(row, colp, E, dis, cursor, iw);
  k_init<<<(N * 16 + 255) / 256, 256, 0, stream>>>(ue, ie, out, xbf0, Nu, N);
  k_prepw<<<192, 256, 0, stream>>>(W1, b1, W2, b2, Wf, bbsum);

  unsigned short* xb[2] = { xbf0, xbf1 };
  const int nt = (N + 15) / 16;
  for (int l = 0; l < 3; ++l) {
    int pcol = l * 64;
    int lcol = (l + 1) * 64;
    k_layer<<<nt, 128, 0, stream>>>(rowptr, iw, xb[l & 1], xb[(l + 1) & 1], out,
                                    Wf + (size_t)l * 16384, bbsum + (size_t)l * 64,
                                    N, pcol, lcol, (l < 2) ? 1 : 0);
  }
}